// Round 10
// baseline (209.155 us; speedup 1.0000x reference)
//
#include <hip/hip_runtime.h>

typedef __bf16 bf16_t;
typedef __bf16 bf16x4_t __attribute__((ext_vector_type(4)));
typedef __bf16 bf16x8 __attribute__((ext_vector_type(8)));
typedef float f32x4 __attribute__((ext_vector_type(4)));

#define NH 8
#define DH 32
#define QL 256
#define KL 256
#define CIN 64
#define HD 256  // NH*DH

__device__ __forceinline__ bf16_t f2bf(float x) { return (bf16_t)x; }

__device__ __forceinline__ f32x4 mfma16(bf16x8 a, bf16x8 b, f32x4 c) {
    return __builtin_amdgcn_mfma_f32_16x16x32_bf16(a, b, c, 0, 0, 0);
}

__device__ __forceinline__ bf16x8 cvt8(const float* __restrict__ p) {
    const f32x4 lo = *(const f32x4*)p;
    const f32x4 hi = *(const f32x4*)(p + 4);
    bf16x8 r;
#pragma unroll
    for (int j = 0; j < 4; ++j) { r[j] = f2bf(lo[j]); r[4 + j] = f2bf(hi[j]); }
    return r;
}

// ---------------------------------------------------------------------------
// Phase 1: high-TLP projection, 2-wide ILP (r9-proven). Flat grid 3072 =
// (s, h, which), XCD swizzle (b&7 -> 16-s band, L2-resident X). 4 blocks/CU.
//   Qf/Kf per (s,h): 16 tiles x [lane][8], elem = M[tile*16+l16][quad*8+j]
//   Vf  per (s,h): 16 chunks x [lane][8],  elem = V[cs*32+quad*8+j][nt*16+l16]
__launch_bounds__(256, 4)
__global__ void proj_v2(const float* __restrict__ Xq, const float* __restrict__ Xkv,
                        const float* __restrict__ Wq, const float* __restrict__ Wk,
                        const float* __restrict__ Wv,
                        bf16_t* __restrict__ Qf, bf16_t* __restrict__ Kf,
                        bf16_t* __restrict__ Vf) {
    const int b = blockIdx.x;
    const int s  = (b & 7) * 16 + ((b >> 3) & 15);  // XCD swizzle
    const int sl = b >> 7;
    const int h  = sl & 7;
    const int which = sl >> 3;                      // 0=Q 1=K 2=V
    const int tid = threadIdx.x, lane = tid & 63, w = tid >> 6;
    const int quad = lane >> 4, l16 = lane & 15;
    const f32x4 vzero = {0.f, 0.f, 0.f, 0.f};

    __shared__ __attribute__((aligned(16))) bf16_t sWT[DH][CIN + 8];   // 4.6 KB
    __shared__ __attribute__((aligned(16))) bf16_t sT[4][2][32][40];   // 20.5 KB (2-wide ILP)

    const float* __restrict__ X = (which == 0) ? Xq : Xkv;
    const float* __restrict__ W = (which == 0) ? Wq : (which == 1 ? Wk : Wv);
    const float scale = (which == 0) ? 0.17677669529663687f : 1.0f;  // 1/sqrt(32)

    // stage W^T head-slice: sWT[d][k], coalesced f32x4
#pragma unroll
    for (int it = 0; it < 2; ++it) {
        const int idx = it * 256 + tid;
        const int k = idx >> 3, c4 = (idx & 7) << 2;
        const f32x4 w4 = *(const f32x4*)&W[k * HD + h * DH + c4];
#pragma unroll
        for (int j = 0; j < 4; ++j) sWT[c4 + j][k] = f2bf(w4[j]);
    }
    __syncthreads();

    // weight B-frags: B[k=ks*32+quad*8+j][n=nt*16+l16]
    bf16x8 bw[2][2];
#pragma unroll
    for (int nt = 0; nt < 2; ++nt)
#pragma unroll
        for (int ks = 0; ks < 2; ++ks)
            bw[nt][ks] = *(const bf16x8*)&sWT[nt * 16 + l16][ks * 32 + quad * 8];

    const size_t base = (size_t)(s * NH + h) * 8192;

    if (which < 2) {
        bf16_t* __restrict__ Dst = which ? Kf : Qf;
#pragma unroll 1
        for (int tp = 0; tp < 2; ++tp) {
            const int mtA = tp * 8 + w, mtB = tp * 8 + w + 4;
            const float* xpA = &X[(s * QL + mtA * 16 + l16) * CIN + quad * 8];
            const float* xpB = &X[(s * QL + mtB * 16 + l16) * CIN + quad * 8];
            const bf16x8 aA0 = cvt8(xpA), aA1 = cvt8(xpA + 32);
            const bf16x8 aB0 = cvt8(xpB), aB1 = cvt8(xpB + 32);
            f32x4 cA0 = vzero, cA1 = vzero, cB0 = vzero, cB1 = vzero;
            cA0 = mfma16(aA0, bw[0][0], cA0);
            cB0 = mfma16(aB0, bw[0][0], cB0);
            cA0 = mfma16(aA1, bw[0][1], cA0);
            cB0 = mfma16(aB1, bw[0][1], cB0);
            cA1 = mfma16(aA0, bw[1][0], cA1);
            cB1 = mfma16(aB0, bw[1][0], cB1);
            cA1 = mfma16(aA1, bw[1][1], cA1);
            cB1 = mfma16(aB1, bw[1][1], cB1);
#pragma unroll
            for (int nt = 0; nt < 2; ++nt) {
                const f32x4 cA = nt ? cA1 : cA0;
                const f32x4 cB = nt ? cB1 : cB0;
#pragma unroll
                for (int r = 0; r < 4; ++r) {
                    sT[w][0][quad * 4 + r][nt * 16 + l16] = f2bf(cA[r] * scale);
                    sT[w][1][quad * 4 + r][nt * 16 + l16] = f2bf(cB[r] * scale);
                }
            }
            const bf16x8 fragA = *(const bf16x8*)&sT[w][0][l16][quad * 8];
            const bf16x8 fragB = *(const bf16x8*)&sT[w][1][l16][quad * 8];
            *(bf16x8*)&Dst[base + (size_t)mtA * 512 + lane * 8] = fragA;
            *(bf16x8*)&Dst[base + (size_t)mtB * 512 + lane * 8] = fragB;
        }
    } else {
        const int csA = w, csB = w + 4;
        bf16x8 aA[2][2], aB[2][2];
#pragma unroll
        for (int u = 0; u < 2; ++u) {
            const float* xpA = &Xkv[(s * KL + csA * 32 + u * 16 + l16) * CIN + quad * 8];
            const float* xpB = &Xkv[(s * KL + csB * 32 + u * 16 + l16) * CIN + quad * 8];
            aA[u][0] = cvt8(xpA); aA[u][1] = cvt8(xpA + 32);
            aB[u][0] = cvt8(xpB); aB[u][1] = cvt8(xpB + 32);
        }
#pragma unroll
        for (int u = 0; u < 2; ++u)
#pragma unroll
            for (int nth = 0; nth < 2; ++nth) {
                f32x4 cA = mfma16(aA[u][0], bw[nth][0], vzero);
                f32x4 cB = mfma16(aB[u][0], bw[nth][0], vzero);
                cA = mfma16(aA[u][1], bw[nth][1], cA);
                cB = mfma16(aB[u][1], bw[nth][1], cB);
#pragma unroll
                for (int r = 0; r < 4; ++r) {
                    sT[w][0][nth * 16 + l16][u * 16 + quad * 4 + r] = f2bf(cA[r]);
                    sT[w][1][nth * 16 + l16][u * 16 + quad * 4 + r] = f2bf(cB[r]);
                }
            }
#pragma unroll
        for (int nt = 0; nt < 2; ++nt) {
            const bf16x8 fA = *(const bf16x8*)&sT[w][0][nt * 16 + l16][quad * 8];
            const bf16x8 fB = *(const bf16x8*)&sT[w][1][nt * 16 + l16][quad * 8];
            *(bf16x8*)&Vf[base + (size_t)(csA * 2 + nt) * 512 + lane * 8] = fA;
            *(bf16x8*)&Vf[base + (size_t)(csB * 2 + nt) * 512 + lane * 8] = fB;
        }
    }
}

// ---------------------------------------------------------------------------
// Phase 2 (fused attention + output projection). grid (128 s, 4 qt) = 512
// blocks; id = s + 128*qt => all 4 qt-blocks of an s on the SAME XCD (the
// r7-proven L2-sharing property). Each wave: ONE 16-row q-tile, loops all 8
// heads (independent iterations -> cross-head ILP), accumulating
// sum_h O_h @ Wo_h in 16 f32 regs. Wo staged to LDS once per block. Writes
// final f32 Out directly — no Ows round-trip, no third kernel.
// launch_bounds(256,3): 170-VGPR budget (sv 64 + acc 16 + transients; r8
// lesson: tighter budgets spill sv to scratch at 10x traffic cost).
__launch_bounds__(256, 3)
__global__ void attn_fused(const float* __restrict__ Mask, const float* __restrict__ Bias,
                           const float* __restrict__ Wo, const float* __restrict__ Bo,
                           const bf16_t* __restrict__ Qf, const bf16_t* __restrict__ Kf,
                           const bf16_t* __restrict__ Vf, float* __restrict__ Out) {
    const int s = blockIdx.x, qt = blockIdx.y;
    const int tid = threadIdx.x, lane = tid & 63, w = tid >> 6;
    const int quad = lane >> 4, l16 = lane & 15;
    const f32x4 vzero = {0.f, 0.f, 0.f, 0.f};

    __shared__ __attribute__((aligned(16))) bf16_t sWoT[CIN][HD + 8];  // 33.8 KB [n=cq][k=hd]
    __shared__ __attribute__((aligned(16))) bf16_t sPT[4][16][136];    // 17.4 KB
    __shared__ float sMt[KL];                                          // 1 KB
    __shared__ float sBo[CIN];

    // stage Wo^T (coalesced f32x4, 16/thread) + mask + bo
#pragma unroll
    for (int it = 0; it < 16; ++it) {
        const int idx = it * 256 + tid;
        const int kk = idx >> 4, c4 = (idx & 15) << 2;
        const f32x4 w4 = *(const f32x4*)&Wo[kk * CIN + c4];
#pragma unroll
        for (int j = 0; j < 4; ++j) sWoT[c4 + j][kk] = f2bf(w4[j]);
    }
    sMt[tid] = (Mask[s * KL + tid] - 1.0f) * 1.0e9f;
    if (tid < CIN) sBo[tid] = Bo[tid];
    __syncthreads();

    const int tile = qt * 4 + w, q0 = tile * 16;

    f32x4 acc[4];
#pragma unroll
    for (int nt = 0; nt < 4; ++nt) acc[nt] = vzero;

#pragma unroll 1
    for (int h = 0; h < NH; ++h) {
        const size_t base = (size_t)(s * NH + h) * 8192;

        const bf16x8 qfr = *(const bf16x8*)&Qf[base + (size_t)tile * 512 + lane * 8];

        // S' = K·Q^T: C/D row=kv-local (quad*4+r), col=q (l16)
        f32x4 sv[16];
#pragma unroll
        for (int ct = 0; ct < 16; ++ct) {
            const bf16x8 ak = *(const bf16x8*)&Kf[base + ct * 512 + lane * 8];
            sv[ct] = mfma16(ak, qfr, vzero);
        }
        const float* bbase = &Bias[(size_t)(h * QL + q0 + l16) * KL];
#pragma unroll
        for (int ct = 0; ct < 16; ++ct) {
            const f32x4 b4 = *(const f32x4*)&bbase[ct * 16 + quad * 4];
            const f32x4 m4 = *(const f32x4*)&sMt[ct * 16 + quad * 4];
            sv[ct] = sv[ct] + b4 + m4;
        }
        // softmax over kv: per-lane 64 values + xor 16/32 across quads
        float mx = -1e30f;
#pragma unroll
        for (int ct = 0; ct < 16; ++ct)
#pragma unroll
            for (int r = 0; r < 4; ++r) mx = fmaxf(mx, sv[ct][r]);
        mx = fmaxf(mx, __shfl_xor(mx, 16, 64));
        mx = fmaxf(mx, __shfl_xor(mx, 32, 64));
        float sum = 0.f;
#pragma unroll
        for (int ct = 0; ct < 16; ++ct)
#pragma unroll
            for (int r = 0; r < 4; ++r) {
                const float e = __expf(sv[ct][r] - mx);
                sv[ct][r] = e;
                sum += e;
            }
        sum += __shfl_xor(sum, 16, 64);
        sum += __shfl_xor(sum, 32, 64);
        const float rs = 1.0f / sum;

        // PV in two 128-kv chunks: normalized P^T -> sPT -> A-frags; V from ws
        f32x4 o0 = vzero, o1 = vzero;
#pragma unroll
        for (int c = 0; c < 2; ++c) {
#pragma unroll
            for (int cc = 0; cc < 8; ++cc) {
                const int ct = c * 8 + cc;
                bf16x4_t pv;
#pragma unroll
                for (int r = 0; r < 4; ++r) pv[r] = f2bf(sv[ct][r] * rs);
                *(bf16x4_t*)&sPT[w][l16][cc * 16 + quad * 4] = pv;
            }
#pragma unroll
            for (int ks = 0; ks < 4; ++ks) {
                const bf16x8 ap = *(const bf16x8*)&sPT[w][l16][ks * 32 + quad * 8];
                const int cs = c * 4 + ks;
                const bf16x8 bv0 = *(const bf16x8*)&Vf[base + (size_t)(cs * 2 + 0) * 512 + lane * 8];
                const bf16x8 bv1 = *(const bf16x8*)&Vf[base + (size_t)(cs * 2 + 1) * 512 + lane * 8];
                o0 = mfma16(ap, bv0, o0);
                o1 = mfma16(ap, bv1, o1);
            }
        }
        // O tile C-layout (q=quad*4+r, d=nt*16+l16) -> sPT[q][d] -> A-frag
        // (same-wave LDS RT; sPT reuse is safe: ap reads completed above)
#pragma unroll
        for (int nt = 0; nt < 2; ++nt) {
            const f32x4 o = nt ? o1 : o0;
#pragma unroll
            for (int r = 0; r < 4; ++r)
                sPT[w][quad * 4 + r][nt * 16 + l16] = f2bf(o[r]);
        }
        const bf16x8 ao = *(const bf16x8*)&sPT[w][l16][quad * 8];
        // acc += O_h @ Wo_h: B[k=h*32+quad*8+j][n=nt*16+l16] from sWoT
#pragma unroll
        for (int nt = 0; nt < 4; ++nt) {
            const bf16x8 bwo = *(const bf16x8*)&sWoT[nt * 16 + l16][h * DH + quad * 8];
            acc[nt] = mfma16(ao, bwo, acc[nt]);
        }
    }

    // epilogue: Out[s*256 + q0 + qr][cq] = acc + bo (f32, coalesced)
#pragma unroll
    for (int nt = 0; nt < 4; ++nt) {
        const float bo = sBo[nt * 16 + l16];
#pragma unroll
        for (int r = 0; r < 4; ++r)
            Out[(size_t)(s * QL + q0 + quad * 4 + r) * CIN + nt * 16 + l16] = acc[nt][r] + bo;
    }
}

extern "C" void kernel_launch(void* const* d_in, const int* in_sizes, int n_in,
                              void* d_out, int out_size, void* d_ws, size_t ws_size,
                              hipStream_t stream) {
    const float* Xq   = (const float*)d_in[0];
    const float* Xkv  = (const float*)d_in[1];
    const float* Mask = (const float*)d_in[2];
    const float* Bias = (const float*)d_in[3];
    const float* Wq   = (const float*)d_in[4];
    const float* Wk   = (const float*)d_in[5];
    const float* Wv   = (const float*)d_in[6];
    const float* Wo   = (const float*)d_in[7];
    const float* Bo   = (const float*)d_in[8];
    float* Out = (float*)d_out;

    const size_t SEG = 16777216;  // 16 MiB; ws >= 48 MiB proven in r5-r9
    bf16_t* Qf = (bf16_t*)d_ws;
    bf16_t* Kf = (bf16_t*)((char*)d_ws + SEG);
    bf16_t* Vf = (bf16_t*)((char*)d_ws + 2 * SEG);

    proj_v2<<<3072, 256, 0, stream>>>(Xq, Xkv, Wq, Wk, Wv, Qf, Kf, Vf);
    attn_fused<<<dim3(128, 4), 256, 0, stream>>>(Mask, Bias, Wo, Bo, Qf, Kf, Vf, Out);
}

// Round 11
// 173.747 us; speedup vs baseline: 1.2038x; 1.2038x over previous
//
#include <hip/hip_runtime.h>

typedef __bf16 bf16_t;
typedef __bf16 bf16x4_t __attribute__((ext_vector_type(4)));
typedef __bf16 bf16x8 __attribute__((ext_vector_type(8)));
typedef float f32x4 __attribute__((ext_vector_type(4)));

#define NH 8
#define DH 32
#define QL 256
#define KL 256
#define CIN 64
#define HD 256  // NH*DH

__device__ __forceinline__ bf16_t f2bf(float x) { return (bf16_t)x; }

__device__ __forceinline__ f32x4 mfma16(bf16x8 a, bf16x8 b, f32x4 c) {
    return __builtin_amdgcn_mfma_f32_16x16x32_bf16(a, b, c, 0, 0, 0);
}

__device__ __forceinline__ bf16x8 cvt8(const float* __restrict__ p) {
    const f32x4 lo = *(const f32x4*)p;
    const f32x4 hi = *(const f32x4*)(p + 4);
    bf16x8 r;
#pragma unroll
    for (int j = 0; j < 4; ++j) { r[j] = f2bf(lo[j]); r[4 + j] = f2bf(hi[j]); }
    return r;
}

// ---------------------------------------------------------------------------
// Phase 1: high-TLP projection, 2-wide ILP (r9-proven, unchanged). Flat grid
// 3072 = (s, h, which), XCD swizzle (b&7 -> 16-s band). 4 blocks/CU.
//   Qf/Kf per (s,h): 16 tiles x [lane][8], elem = M[tile*16+l16][quad*8+j]
//   Vf  per (s,h): 16 chunks x [lane][8],  elem = V[cs*32+quad*8+j][nt*16+l16]
__launch_bounds__(256, 4)
__global__ void proj_v2(const float* __restrict__ Xq, const float* __restrict__ Xkv,
                        const float* __restrict__ Wq, const float* __restrict__ Wk,
                        const float* __restrict__ Wv,
                        bf16_t* __restrict__ Qf, bf16_t* __restrict__ Kf,
                        bf16_t* __restrict__ Vf) {
    const int b = blockIdx.x;
    const int s  = (b & 7) * 16 + ((b >> 3) & 15);  // XCD swizzle
    const int sl = b >> 7;
    const int h  = sl & 7;
    const int which = sl >> 3;                      // 0=Q 1=K 2=V
    const int tid = threadIdx.x, lane = tid & 63, w = tid >> 6;
    const int quad = lane >> 4, l16 = lane & 15;
    const f32x4 vzero = {0.f, 0.f, 0.f, 0.f};

    __shared__ __attribute__((aligned(16))) bf16_t sWT[DH][CIN + 8];   // 4.6 KB
    __shared__ __attribute__((aligned(16))) bf16_t sT[4][2][32][40];   // 20.5 KB (2-wide ILP)

    const float* __restrict__ X = (which == 0) ? Xq : Xkv;
    const float* __restrict__ W = (which == 0) ? Wq : (which == 1 ? Wk : Wv);
    const float scale = (which == 0) ? 0.17677669529663687f : 1.0f;  // 1/sqrt(32)

    // stage W^T head-slice: sWT[d][k], coalesced f32x4
#pragma unroll
    for (int it = 0; it < 2; ++it) {
        const int idx = it * 256 + tid;
        const int k = idx >> 3, c4 = (idx & 7) << 2;
        const f32x4 w4 = *(const f32x4*)&W[k * HD + h * DH + c4];
#pragma unroll
        for (int j = 0; j < 4; ++j) sWT[c4 + j][k] = f2bf(w4[j]);
    }
    __syncthreads();

    // weight B-frags: B[k=ks*32+quad*8+j][n=nt*16+l16]
    bf16x8 bw[2][2];
#pragma unroll
    for (int nt = 0; nt < 2; ++nt)
#pragma unroll
        for (int ks = 0; ks < 2; ++ks)
            bw[nt][ks] = *(const bf16x8*)&sWT[nt * 16 + l16][ks * 32 + quad * 8];

    const size_t base = (size_t)(s * NH + h) * 8192;

    if (which < 2) {
        bf16_t* __restrict__ Dst = which ? Kf : Qf;
#pragma unroll 1
        for (int tp = 0; tp < 2; ++tp) {
            const int mtA = tp * 8 + w, mtB = tp * 8 + w + 4;
            const float* xpA = &X[(s * QL + mtA * 16 + l16) * CIN + quad * 8];
            const float* xpB = &X[(s * QL + mtB * 16 + l16) * CIN + quad * 8];
            const bf16x8 aA0 = cvt8(xpA), aA1 = cvt8(xpA + 32);
            const bf16x8 aB0 = cvt8(xpB), aB1 = cvt8(xpB + 32);
            f32x4 cA0 = vzero, cA1 = vzero, cB0 = vzero, cB1 = vzero;
            cA0 = mfma16(aA0, bw[0][0], cA0);
            cB0 = mfma16(aB0, bw[0][0], cB0);
            cA0 = mfma16(aA1, bw[0][1], cA0);
            cB0 = mfma16(aB1, bw[0][1], cB0);
            cA1 = mfma16(aA0, bw[1][0], cA1);
            cB1 = mfma16(aB0, bw[1][0], cB1);
            cA1 = mfma16(aA1, bw[1][1], cA1);
            cB1 = mfma16(aB1, bw[1][1], cB1);
#pragma unroll
            for (int nt = 0; nt < 2; ++nt) {
                const f32x4 cA = nt ? cA1 : cA0;
                const f32x4 cB = nt ? cB1 : cB0;
#pragma unroll
                for (int r = 0; r < 4; ++r) {
                    sT[w][0][quad * 4 + r][nt * 16 + l16] = f2bf(cA[r] * scale);
                    sT[w][1][quad * 4 + r][nt * 16 + l16] = f2bf(cB[r] * scale);
                }
            }
            const bf16x8 fragA = *(const bf16x8*)&sT[w][0][l16][quad * 8];
            const bf16x8 fragB = *(const bf16x8*)&sT[w][1][l16][quad * 8];
            *(bf16x8*)&Dst[base + (size_t)mtA * 512 + lane * 8] = fragA;
            *(bf16x8*)&Dst[base + (size_t)mtB * 512 + lane * 8] = fragB;
        }
    } else {
        const int csA = w, csB = w + 4;
        bf16x8 aA[2][2], aB[2][2];
#pragma unroll
        for (int u = 0; u < 2; ++u) {
            const float* xpA = &Xkv[(s * KL + csA * 32 + u * 16 + l16) * CIN + quad * 8];
            const float* xpB = &Xkv[(s * KL + csB * 32 + u * 16 + l16) * CIN + quad * 8];
            aA[u][0] = cvt8(xpA); aA[u][1] = cvt8(xpA + 32);
            aB[u][0] = cvt8(xpB); aB[u][1] = cvt8(xpB + 32);
        }
#pragma unroll
        for (int u = 0; u < 2; ++u)
#pragma unroll
            for (int nth = 0; nth < 2; ++nth) {
                f32x4 cA = mfma16(aA[u][0], bw[nth][0], vzero);
                f32x4 cB = mfma16(aB[u][0], bw[nth][0], vzero);
                cA = mfma16(aA[u][1], bw[nth][1], cA);
                cB = mfma16(aB[u][1], bw[nth][1], cB);
#pragma unroll
                for (int r = 0; r < 4; ++r) {
                    sT[w][0][nth * 16 + l16][u * 16 + quad * 4 + r] = f2bf(cA[r]);
                    sT[w][1][nth * 16 + l16][u * 16 + quad * 4 + r] = f2bf(cB[r]);
                }
            }
#pragma unroll
        for (int nt = 0; nt < 2; ++nt) {
            const bf16x8 fA = *(const bf16x8*)&sT[w][0][nt * 16 + l16][quad * 8];
            const bf16x8 fB = *(const bf16x8*)&sT[w][1][nt * 16 + l16][quad * 8];
            *(bf16x8*)&Vf[base + (size_t)(csA * 2 + nt) * 512 + lane * 8] = fA;
            *(bf16x8*)&Vf[base + (size_t)(csB * 2 + nt) * 512 + lane * 8] = fB;
        }
    }
}

// ---------------------------------------------------------------------------
// Phase 2: attention + atomic output-projection. grid (128 s, 4 qt, 8 h) =
// 4096 blocks — attn3's proven parallel shape (r10 lesson: serializing heads
// in-wave costs ~15 µs/head; keep heads as blocks). Each block computes its
// O_h tile, multiplies by the Wo head-slice (8 KB staged per block), and
// atomically accumulates the f32 partial into Out (zeroed by memset).
// bias+mask ride the MFMA C operand. 4 blocks/CU (128-VGPR budget; r8 lesson).
__launch_bounds__(256, 4)
__global__ void attn4(const float* __restrict__ Mask, const float* __restrict__ Bias,
                      const float* __restrict__ Wo, const float* __restrict__ Bo,
                      const bf16_t* __restrict__ Qf, const bf16_t* __restrict__ Kf,
                      const bf16_t* __restrict__ Vf, float* __restrict__ Out) {
    const int s = blockIdx.x, qt = blockIdx.y, h = blockIdx.z;
    const int tid = threadIdx.x, lane = tid & 63, w = tid >> 6;
    const int quad = lane >> 4, l16 = lane & 15;
    const f32x4 vzero = {0.f, 0.f, 0.f, 0.f};

    __shared__ __attribute__((aligned(16))) bf16_t sPT[4][16][136];  // 17.4 KB
    __shared__ __attribute__((aligned(16))) bf16_t sWoT[CIN][40];    // 5 KB [n=cq][k=d]
    __shared__ float sMt[KL];                                        // 1 KB

    // stage this head's Wo slice (rows h*32..+32 of Wo[256][64]) transposed,
    // and the mask term. One barrier covers both.
#pragma unroll
    for (int it = 0; it < 2; ++it) {
        const int idx = it * 256 + tid;
        const int kk = idx >> 4, c4 = (idx & 15) << 2;   // kk: d in [0,32), c4: cq
        const f32x4 w4 = *(const f32x4*)&Wo[(h * DH + kk) * CIN + c4];
#pragma unroll
        for (int j = 0; j < 4; ++j) sWoT[c4 + j][kk] = f2bf(w4[j]);
    }
    sMt[tid] = (Mask[s * KL + tid] - 1.0f) * 1.0e9f;
    __syncthreads();

    const int tile = qt * 4 + w, q0 = tile * 16;
    const size_t base = (size_t)(s * NH + h) * 8192;

    const bf16x8 qfr = *(const bf16x8*)&Qf[base + (size_t)tile * 512 + lane * 8];

    // sv = bias + mask (issues loads early), then S' = K·Q^T accumulated on top
    f32x4 sv[16];
    const float* bbase = &Bias[(size_t)(h * QL + q0 + l16) * KL];
#pragma unroll
    for (int ct = 0; ct < 16; ++ct) {
        const f32x4 b4 = *(const f32x4*)&bbase[ct * 16 + quad * 4];
        const f32x4 m4 = *(const f32x4*)&sMt[ct * 16 + quad * 4];
        sv[ct] = b4 + m4;
    }
#pragma unroll
    for (int ct = 0; ct < 16; ++ct) {
        const bf16x8 ak = *(const bf16x8*)&Kf[base + ct * 512 + lane * 8];
        sv[ct] = mfma16(ak, qfr, sv[ct]);  // C/D row=kv-local (quad*4+r), col=q (l16)
    }
    // softmax over kv: per-lane 64 values + xor 16/32 across quads
    float mx = -1e30f;
#pragma unroll
    for (int ct = 0; ct < 16; ++ct)
#pragma unroll
        for (int r = 0; r < 4; ++r) mx = fmaxf(mx, sv[ct][r]);
    mx = fmaxf(mx, __shfl_xor(mx, 16, 64));
    mx = fmaxf(mx, __shfl_xor(mx, 32, 64));
    float sum = 0.f;
#pragma unroll
    for (int ct = 0; ct < 16; ++ct)
#pragma unroll
        for (int r = 0; r < 4; ++r) {
            const float e = __expf(sv[ct][r] - mx);
            sv[ct][r] = e;
            sum += e;
        }
    sum += __shfl_xor(sum, 16, 64);
    sum += __shfl_xor(sum, 32, 64);
    const float rs = 1.0f / sum;

    // PV in two 128-kv chunks: normalized P^T -> sPT -> A-frags; V from ws
    f32x4 o0 = vzero, o1 = vzero;
#pragma unroll
    for (int c = 0; c < 2; ++c) {
#pragma unroll
        for (int cc = 0; cc < 8; ++cc) {
            const int ct = c * 8 + cc;
            bf16x4_t pv;
#pragma unroll
            for (int r = 0; r < 4; ++r) pv[r] = f2bf(sv[ct][r] * rs);
            *(bf16x4_t*)&sPT[w][l16][cc * 16 + quad * 4] = pv;
        }
#pragma unroll
        for (int ks = 0; ks < 4; ++ks) {
            const bf16x8 ap = *(const bf16x8*)&sPT[w][l16][ks * 32 + quad * 8];
            const int cs = c * 4 + ks;
            const bf16x8 bv0 = *(const bf16x8*)&Vf[base + (size_t)(cs * 2 + 0) * 512 + lane * 8];
            const bf16x8 bv1 = *(const bf16x8*)&Vf[base + (size_t)(cs * 2 + 1) * 512 + lane * 8];
            o0 = mfma16(ap, bv0, o0);
            o1 = mfma16(ap, bv1, o1);
        }
    }

    // epilogue: O tile (C-layout) -> sPT[q][d] -> A-frag, then O_h @ Wo_h
    // (same-wave LDS RT; sPT reuse safe — ap reads completed above)
#pragma unroll
    for (int nt = 0; nt < 2; ++nt) {
        const f32x4 o = nt ? o1 : o0;
#pragma unroll
        for (int r = 0; r < 4; ++r)
            sPT[w][quad * 4 + r][nt * 16 + l16] = f2bf(o[r]);
    }
    const bf16x8 ao = *(const bf16x8*)&sPT[w][l16][quad * 8];
    f32x4 acc[4];
#pragma unroll
    for (int nt = 0; nt < 4; ++nt) {
        const bf16x8 bwo = *(const bf16x8*)&sWoT[nt * 16 + l16][quad * 8];
        acc[nt] = mfma16(ao, bwo, vzero);
    }
    // h==0 blocks fold in the output bias (exactly once per output element)
    if (h == 0) {
#pragma unroll
        for (int nt = 0; nt < 4; ++nt) {
            const float bo = Bo[nt * 16 + l16];
#pragma unroll
            for (int r = 0; r < 4; ++r) acc[nt][r] += bo;
        }
    }
    // atomic accumulate the head partial into Out (C-layout: row=quad*4+r)
    float* obase = &Out[(size_t)(s * QL + q0 + quad * 4) * CIN];
#pragma unroll
    for (int nt = 0; nt < 4; ++nt)
#pragma unroll
        for (int r = 0; r < 4; ++r)
            unsafeAtomicAdd(&obase[r * CIN + nt * 16 + l16], acc[nt][r]);
}

extern "C" void kernel_launch(void* const* d_in, const int* in_sizes, int n_in,
                              void* d_out, int out_size, void* d_ws, size_t ws_size,
                              hipStream_t stream) {
    const float* Xq   = (const float*)d_in[0];
    const float* Xkv  = (const float*)d_in[1];
    const float* Mask = (const float*)d_in[2];
    const float* Bias = (const float*)d_in[3];
    const float* Wq   = (const float*)d_in[4];
    const float* Wk   = (const float*)d_in[5];
    const float* Wv   = (const float*)d_in[6];
    const float* Wo   = (const float*)d_in[7];
    const float* Bo   = (const float*)d_in[8];
    float* Out = (float*)d_out;

    const size_t SEG = 16777216;  // 16 MiB; ws >= 48 MiB proven in r5-r10
    bf16_t* Qf = (bf16_t*)d_ws;
    bf16_t* Kf = (bf16_t*)((char*)d_ws + SEG);
    bf16_t* Vf = (bf16_t*)((char*)d_ws + 2 * SEG);

    // Out accumulates head partials atomically — zero it first (memset node
    // is graph-capture legal; harness poisons d_out before every launch).
    hipMemsetAsync(Out, 0, (size_t)out_size * sizeof(float), stream);
    proj_v2<<<3072, 256, 0, stream>>>(Xq, Xkv, Wq, Wk, Wv, Qf, Kf, Vf);
    attn4<<<dim3(128, 4, NH), 256, 0, stream>>>(Mask, Bias, Wo, Bo, Qf, Kf, Vf, Out);
}